// Round 4
// baseline (2575.180 us; speedup 1.0000x reference)
//
#include <hip/hip_runtime.h>
#include <hip/hip_bf16.h>
#include <cstdint>

#define D_DIM 2048
#define F_DIM 1024
#define E_NUM 64
#define K_TOP 8
#define CAP   1024
#define PITCH 144

typedef __attribute__((ext_vector_type(8))) short short8;
typedef __attribute__((ext_vector_type(4))) float f32x4;

__device__ __forceinline__ uint16_t f_to_bf16(float f) {
    union { float f; uint32_t u; } v; v.f = f;
    uint32_t r = v.u + 0x7FFF + ((v.u >> 16) & 1);
    return (uint16_t)(r >> 16);
}
__device__ __forceinline__ uint32_t pack2(float a, float b) {
    __hip_bfloat162 t = __float22bfloat162_rn(make_float2(a, b));
    return *reinterpret_cast<uint32_t*>(&t);
}

// ---------------- x -> bf16 ----------------
__global__ __launch_bounds__(256) void cvtx_k(const float* __restrict__ x,
        uint16_t* __restrict__ xb, int n8) {
    int i = blockIdx.x * 256 + threadIdx.x;
    if (i >= n8) return;
    const float4* p = (const float4*)x + (size_t)i * 2;
    float4 a = p[0], b = p[1];
    uint4 o;
    o.x = pack2(a.x, a.y); o.y = pack2(a.z, a.w);
    o.z = pack2(b.x, b.y); o.w = pack2(b.z, b.w);
    ((uint4*)xb)[i] = o;
}

// ---------------- Router ----------------
__global__ __launch_bounds__(64) void router_k(const float* __restrict__ x,
        const float* __restrict__ gw, int* __restrict__ topi,
        float* __restrict__ topw) {
    int t = blockIdx.x;
    int tid = threadIdx.x;
    __shared__ float xs[D_DIM];
    __shared__ float lgs[E_NUM];
    const float* xr = x + (size_t)t * D_DIM;
    for (int d = tid; d < D_DIM; d += 64) xs[d] = xr[d];
    __syncthreads();
    const float* w = gw + (size_t)tid * D_DIM;
    float acc = 0.f;
    #pragma unroll 8
    for (int d = 0; d < D_DIM; ++d) acc = fmaf(xs[d], w[d], acc);
    lgs[tid] = acc;
    __syncthreads();
    if (tid == 0) {
        float mx = -INFINITY;
        for (int e = 0; e < E_NUM; ++e) mx = fmaxf(mx, lgs[e]);
        float se = 0.f;
        for (int e = 0; e < E_NUM; ++e) se += expf(lgs[e] - mx);
        float inv = 1.f / se;
        uint64_t used = 0;
        for (int k = 0; k < K_TOP; ++k) {
            int bi = 0; float bv = -INFINITY;
            for (int e = 0; e < E_NUM; ++e) {
                if (!((used >> e) & 1) && lgs[e] > bv) { bv = lgs[e]; bi = e; }
            }
            used |= 1ull << bi;
            topi[t * K_TOP + k] = bi;
            topw[t * K_TOP + k] = expf(bv - mx) * inv;
        }
    }
}

// ---------------- Slot assignment ----------------
__global__ void assign_k(const int* __restrict__ topi, const float* __restrict__ topw,
        int* __restrict__ cnt, int* __restrict__ rowtok, float* __restrict__ aw, int T) {
    int t = blockIdx.x * blockDim.x + threadIdx.x;
    if (t >= T) return;
    for (int k = 0; k < K_TOP; ++k) {
        int e = topi[t * K_TOP + k];
        int pos = atomicAdd(&cnt[e], 1);
        if (pos < CAP) {
            rowtok[e * CAP + pos] = t;
            aw[e * CAP + pos] = topw[t * K_TOP + k];
        }
    }
}

// ------- Gate+Up GEMM: 256m x 128f, BK=64, 512 thr, reg-prefetch pipeline -------
__global__ __launch_bounds__(512, 2) void gateup_k(const uint16_t* __restrict__ xb,
        const float* __restrict__ wg, const float* __restrict__ wu,
        const int* __restrict__ cnt, const int* __restrict__ rowtok,
        uint16_t* __restrict__ h) {
    int flat = blockIdx.x;
    int xcd = flat & 7;
    int idx = flat >> 3;
    int m = idx & 3;
    int sloc = idx >> 2;              // 0..63
    int strip = sloc * 8 + xcd;       // e*8 + f
    int e = strip >> 3;
    int f = strip & 7;
    int m0 = m * 256;
    int ne = min(cnt[e], CAP);
    int nr = ne - m0;
    if (nr <= 0) return;
    if (nr > 256) nr = 256;
    int slot0 = e * CAP + m0;
    int fbase = f * 128;

    __shared__ __align__(16) unsigned char Asm[256 * PITCH];
    __shared__ __align__(16) unsigned char Bgm[128 * PITCH];
    __shared__ __align__(16) unsigned char Bum[128 * PITCH];

    int tid = threadIdx.x;
    int l = tid & 63, wid = tid >> 6;
    int wr = wid >> 1, wc = wid & 1;  // 4m x 2f waves, wave tile 64x64
    int ln = l & 15, lq = l >> 4;

    // A staging: 4 units; unit i: row = i*64 + tid/8, chunk = tid&7 (8 lanes/row -> 128B segs)
    int ach = tid & 7;
    const uint16_t* asrc[4];
    uint32_t aoff[4];
    #pragma unroll
    for (int i = 0; i < 4; ++i) {
        int row = i * 64 + (tid >> 3);
        int tok = rowtok[slot0 + min(row, nr - 1)];
        asrc[i] = xb + (size_t)tok * D_DIM + ach * 8;
        aoff[i] = row * PITCH + ach * 16;
    }
    // B staging: col pair (f) per lane, 8 k-rows per thread (chunk = wid)
    int bcol = (tid & 63) * 2;
    size_t wb = (size_t)e * ((size_t)D_DIM * F_DIM) + (size_t)(wid * 8) * F_DIM
              + (size_t)fbase + bcol;
    const float* gp = wg + wb;
    const float* up = wu + wb;
    uint32_t boff0 = (uint32_t)bcol * PITCH + wid * 16;
    uint32_t boff1 = (uint32_t)(bcol + 1) * PITCH + wid * 16;

    f32x4 accg[4][4], accu[4][4];
    #pragma unroll
    for (int mi = 0; mi < 4; ++mi)
        #pragma unroll
        for (int ni = 0; ni < 4; ++ni) {
            accg[mi][ni] = (f32x4){0.f, 0.f, 0.f, 0.f};
            accu[mi][ni] = (f32x4){0.f, 0.f, 0.f, 0.f};
        }

    uint4 ra[4];
    uint32_t rg[8], ru[8];
    #pragma unroll
    for (int i = 0; i < 4; ++i) ra[i] = *(const uint4*)(asrc[i]);
    #pragma unroll
    for (int i = 0; i < 8; ++i) {
        float2 g2 = *(const float2*)(gp + (size_t)i * F_DIM);
        float2 u2 = *(const float2*)(up + (size_t)i * F_DIM);
        rg[i] = pack2(g2.x, g2.y);
        ru[i] = pack2(u2.x, u2.y);
    }

    const int NT = D_DIM / 64;  // 32
    for (int t = 0; t < NT; ++t) {
        __syncthreads();
        #pragma unroll
        for (int i = 0; i < 4; ++i) *(uint4*)(Asm + aoff[i]) = ra[i];
        {
            uint4 LO, HI;
            LO.x = (rg[0] & 0xffffu) | (rg[1] << 16);
            LO.y = (rg[2] & 0xffffu) | (rg[3] << 16);
            LO.z = (rg[4] & 0xffffu) | (rg[5] << 16);
            LO.w = (rg[6] & 0xffffu) | (rg[7] << 16);
            HI.x = (rg[0] >> 16) | (rg[1] & 0xffff0000u);
            HI.y = (rg[2] >> 16) | (rg[3] & 0xffff0000u);
            HI.z = (rg[4] >> 16) | (rg[5] & 0xffff0000u);
            HI.w = (rg[6] >> 16) | (rg[7] & 0xffff0000u);
            *(uint4*)(Bgm + boff0) = LO;
            *(uint4*)(Bgm + boff1) = HI;
        }
        {
            uint4 LO, HI;
            LO.x = (ru[0] & 0xffffu) | (ru[1] << 16);
            LO.y = (ru[2] & 0xffffu) | (ru[3] << 16);
            LO.z = (ru[4] & 0xffffu) | (ru[5] << 16);
            LO.w = (ru[6] & 0xffffu) | (ru[7] << 16);
            HI.x = (ru[0] >> 16) | (ru[1] & 0xffff0000u);
            HI.y = (ru[2] >> 16) | (ru[3] & 0xffff0000u);
            HI.z = (ru[4] >> 16) | (ru[5] & 0xffff0000u);
            HI.w = (ru[6] >> 16) | (ru[7] & 0xffff0000u);
            *(uint4*)(Bum + boff0) = LO;
            *(uint4*)(Bum + boff1) = HI;
        }
        __syncthreads();
        if (t + 1 < NT) {
            #pragma unroll
            for (int i = 0; i < 4; ++i) ra[i] = *(const uint4*)(asrc[i] + (t + 1) * 64);
            size_t ko = (size_t)(t + 1) * 64 * F_DIM;
            #pragma unroll
            for (int i = 0; i < 8; ++i) {
                float2 g2 = *(const float2*)(gp + ko + (size_t)i * F_DIM);
                float2 u2 = *(const float2*)(up + ko + (size_t)i * F_DIM);
                rg[i] = pack2(g2.x, g2.y);
                ru[i] = pack2(u2.x, u2.y);
            }
        }
        #pragma unroll
        for (int kk = 0; kk < 2; ++kk) {
            short8 af[4], bg[4], bu[4];
            #pragma unroll
            for (int mi = 0; mi < 4; ++mi)
                af[mi] = *(const short8*)(Asm + (wr * 64 + mi * 16 + ln) * PITCH + (kk * 4 + lq) * 16);
            #pragma unroll
            for (int ni = 0; ni < 4; ++ni) {
                bg[ni] = *(const short8*)(Bgm + (wc * 64 + ni * 16 + ln) * PITCH + (kk * 4 + lq) * 16);
                bu[ni] = *(const short8*)(Bum + (wc * 64 + ni * 16 + ln) * PITCH + (kk * 4 + lq) * 16);
            }
            #pragma unroll
            for (int mi = 0; mi < 4; ++mi)
                #pragma unroll
                for (int ni = 0; ni < 4; ++ni) {
                    accg[mi][ni] = __builtin_amdgcn_mfma_f32_16x16x32_bf16(af[mi], bg[ni], accg[mi][ni], 0, 0, 0);
                    accu[mi][ni] = __builtin_amdgcn_mfma_f32_16x16x32_bf16(af[mi], bu[ni], accu[mi][ni], 0, 0, 0);
                }
        }
    }

    #pragma unroll
    for (int mi = 0; mi < 4; ++mi) {
        int rb = wr * 64 + mi * 16 + lq * 4;
        #pragma unroll
        for (int j = 0; j < 4; ++j) {
            int row = rb + j;
            if (row < nr) {
                size_t hb = (size_t)(slot0 + row) * F_DIM + fbase + wc * 64 + ln;
                #pragma unroll
                for (int ni = 0; ni < 4; ++ni) {
                    float g = accg[mi][ni][j], u = accu[mi][ni][j];
                    h[hb + ni * 16] = f_to_bf16(g / (1.f + __expf(-g)) * u);
                }
            }
        }
    }
}

// ------- Down GEMM + combine: 256m x 128d, BK=64, 512 thr -------
__global__ __launch_bounds__(512, 2) void down_k(const uint16_t* __restrict__ h,
        const float* __restrict__ wd, const int* __restrict__ cnt,
        const int* __restrict__ rowtok, const float* __restrict__ aw,
        float* __restrict__ out) {
    int flat = blockIdx.x;
    int xcd = flat & 7;
    int idx = flat >> 3;
    int m = idx & 3;
    int sloc = idx >> 2;              // 0..127
    int strip = sloc * 8 + xcd;       // e*16 + dt
    int e = strip >> 4;
    int dt = strip & 15;
    int m0 = m * 256;
    int ne = min(cnt[e], CAP);
    int nr = ne - m0;
    if (nr <= 0) return;
    if (nr > 256) nr = 256;
    int slot0 = e * CAP + m0;
    int dbase = dt * 128;

    __shared__ __align__(16) unsigned char Asm[256 * PITCH];
    __shared__ __align__(16) unsigned char Bsm[128 * PITCH];

    int tid = threadIdx.x;
    int l = tid & 63, wid = tid >> 6;
    int wr = wid >> 1, wc = wid & 1;
    int ln = l & 15, lq = l >> 4;

    int ach = tid & 7;
    const uint16_t* asrc[4];
    uint32_t aoff[4];
    #pragma unroll
    for (int i = 0; i < 4; ++i) {
        int row = i * 64 + (tid >> 3);
        asrc[i] = h + (size_t)(slot0 + min(row, nr - 1)) * F_DIM + ach * 8;
        aoff[i] = row * PITCH + ach * 16;
    }
    int bcol = (tid & 63) * 2;
    const float* bp = wd + (size_t)e * ((size_t)F_DIM * D_DIM) + (size_t)(wid * 8) * D_DIM
                    + (size_t)dbase + bcol;
    uint32_t boff0 = (uint32_t)bcol * PITCH + wid * 16;
    uint32_t boff1 = (uint32_t)(bcol + 1) * PITCH + wid * 16;

    f32x4 acc[4][4];
    #pragma unroll
    for (int mi = 0; mi < 4; ++mi)
        #pragma unroll
        for (int ni = 0; ni < 4; ++ni)
            acc[mi][ni] = (f32x4){0.f, 0.f, 0.f, 0.f};

    uint4 ra[4];
    uint32_t rb[8];
    #pragma unroll
    for (int i = 0; i < 4; ++i) ra[i] = *(const uint4*)(asrc[i]);
    #pragma unroll
    for (int i = 0; i < 8; ++i) {
        float2 b2 = *(const float2*)(bp + (size_t)i * D_DIM);
        rb[i] = pack2(b2.x, b2.y);
    }

    const int NT = F_DIM / 64;  // 16
    for (int t = 0; t < NT; ++t) {
        __syncthreads();
        #pragma unroll
        for (int i = 0; i < 4; ++i) *(uint4*)(Asm + aoff[i]) = ra[i];
        {
            uint4 LO, HI;
            LO.x = (rb[0] & 0xffffu) | (rb[1] << 16);
            LO.y = (rb[2] & 0xffffu) | (rb[3] << 16);
            LO.z = (rb[4] & 0xffffu) | (rb[5] << 16);
            LO.w = (rb[6] & 0xffffu) | (rb[7] << 16);
            HI.x = (rb[0] >> 16) | (rb[1] & 0xffff0000u);
            HI.y = (rb[2] >> 16) | (rb[3] & 0xffff0000u);
            HI.z = (rb[4] >> 16) | (rb[5] & 0xffff0000u);
            HI.w = (rb[6] >> 16) | (rb[7] & 0xffff0000u);
            *(uint4*)(Bsm + boff0) = LO;
            *(uint4*)(Bsm + boff1) = HI;
        }
        __syncthreads();
        if (t + 1 < NT) {
            #pragma unroll
            for (int i = 0; i < 4; ++i) ra[i] = *(const uint4*)(asrc[i] + (t + 1) * 64);
            size_t ko = (size_t)(t + 1) * 64 * D_DIM;
            #pragma unroll
            for (int i = 0; i < 8; ++i) {
                float2 b2 = *(const float2*)(bp + ko + (size_t)i * D_DIM);
                rb[i] = pack2(b2.x, b2.y);
            }
        }
        #pragma unroll
        for (int kk = 0; kk < 2; ++kk) {
            short8 af[4], bf2[4];
            #pragma unroll
            for (int mi = 0; mi < 4; ++mi)
                af[mi] = *(const short8*)(Asm + (wr * 64 + mi * 16 + ln) * PITCH + (kk * 4 + lq) * 16);
            #pragma unroll
            for (int ni = 0; ni < 4; ++ni)
                bf2[ni] = *(const short8*)(Bsm + (wc * 64 + ni * 16 + ln) * PITCH + (kk * 4 + lq) * 16);
            #pragma unroll
            for (int mi = 0; mi < 4; ++mi)
                #pragma unroll
                for (int ni = 0; ni < 4; ++ni)
                    acc[mi][ni] = __builtin_amdgcn_mfma_f32_16x16x32_bf16(af[mi], bf2[ni], acc[mi][ni], 0, 0, 0);
        }
    }

    #pragma unroll
    for (int mi = 0; mi < 4; ++mi) {
        int rb2 = wr * 64 + mi * 16 + lq * 4;
        #pragma unroll
        for (int j = 0; j < 4; ++j) {
            int row = rb2 + j;
            if (row < nr) {
                int slot = slot0 + row;
                int tok = rowtok[slot];
                float wgt = aw[slot];
                float* orow = out + (size_t)tok * D_DIM + dbase + wc * 64 + ln;
                #pragma unroll
                for (int ni = 0; ni < 4; ++ni)
                    atomicAdd(&orow[ni * 16], acc[mi][ni][j] * wgt);
            }
        }
    }
}

extern "C" void kernel_launch(void* const* d_in, const int* in_sizes, int n_in,
                              void* d_out, int out_size, void* d_ws, size_t ws_size,
                              hipStream_t stream) {
    const float* x  = (const float*)d_in[0];
    const float* gw = (const float*)d_in[1];
    const float* wg = (const float*)d_in[2];
    const float* wu = (const float*)d_in[3];
    const float* wd = (const float*)d_in[4];
    float* out = (float*)d_out;
    int T = in_sizes[0] / D_DIM;

    char* ws = (char*)d_ws;
    size_t off = 0;
    auto alloc = [&](size_t bytes) -> void* {
        void* p = ws + off;
        off = (off + bytes + 255) & ~(size_t)255;
        return p;
    };
    int*      cnt    = (int*)     alloc(E_NUM * sizeof(int));
    int*      topi   = (int*)     alloc((size_t)T * K_TOP * sizeof(int));
    float*    topw   = (float*)   alloc((size_t)T * K_TOP * sizeof(float));
    int*      rowtok = (int*)     alloc((size_t)E_NUM * CAP * sizeof(int));
    float*    aw     = (float*)   alloc((size_t)E_NUM * CAP * sizeof(float));
    uint16_t* xb     = (uint16_t*)alloc((size_t)T * D_DIM * sizeof(uint16_t));
    uint16_t* h      = (uint16_t*)alloc((size_t)E_NUM * CAP * F_DIM * sizeof(uint16_t));

    hipMemsetAsync(cnt, 0, E_NUM * sizeof(int), stream);
    hipMemsetAsync(out, 0, (size_t)out_size * sizeof(float), stream);

    int n8 = T * D_DIM / 8;
    cvtx_k<<<(n8 + 255) / 256, 256, 0, stream>>>(x, xb, n8);
    router_k<<<T, 64, 0, stream>>>(x, gw, topi, topw);
    assign_k<<<(T + 255) / 256, 256, 0, stream>>>(topi, topw, cnt, rowtok, aw, T);
    gateup_k<<<E_NUM * 4 * 8, 512, 0, stream>>>(xb, wg, wu, cnt, rowtok, h);
    down_k<<<E_NUM * 16 * 4 * 8 / 8, 512, 0, stream>>>(h, wd, cnt, rowtok, aw, out);
}

// Round 5
// 1933.041 us; speedup vs baseline: 1.3322x; 1.3322x over previous
//
#include <hip/hip_runtime.h>
#include <hip/hip_bf16.h>
#include <cstdint>

#define D_DIM 2048
#define F_DIM 1024
#define E_NUM 64
#define K_TOP 8
#define CAP   1024
#define APITCH 72   // LDS row pitch: 32 bf16 (64B) + 8 pad -> 2-way (free) frag reads

typedef __attribute__((ext_vector_type(8))) short short8;
typedef __attribute__((ext_vector_type(4))) float f32x4;

__device__ __forceinline__ uint16_t f_to_bf16(float f) {
    union { float f; uint32_t u; } v; v.f = f;
    uint32_t r = v.u + 0x7FFF + ((v.u >> 16) & 1);
    return (uint16_t)(r >> 16);
}
__device__ __forceinline__ uint32_t pack2(float a, float b) {
    __hip_bfloat162 t = __float22bfloat162_rn(make_float2(a, b));
    return *reinterpret_cast<uint32_t*>(&t);
}

// ---------------- x -> bf16 ----------------
__global__ __launch_bounds__(256) void cvtx_k(const float* __restrict__ x,
        uint16_t* __restrict__ xb, int n8) {
    int i = blockIdx.x * 256 + threadIdx.x;
    if (i >= n8) return;
    const float4* p = (const float4*)x + (size_t)i * 2;
    float4 a = p[0], b = p[1];
    uint4 o;
    o.x = pack2(a.x, a.y); o.y = pack2(a.z, a.w);
    o.z = pack2(b.x, b.y); o.w = pack2(b.z, b.w);
    ((uint4*)xb)[i] = o;
}

// ---------------- Router ----------------
__global__ __launch_bounds__(64) void router_k(const float* __restrict__ x,
        const float* __restrict__ gw, int* __restrict__ topi,
        float* __restrict__ topw) {
    int t = blockIdx.x;
    int tid = threadIdx.x;
    __shared__ float xs[D_DIM];
    __shared__ float lgs[E_NUM];
    const float* xr = x + (size_t)t * D_DIM;
    for (int d = tid; d < D_DIM; d += 64) xs[d] = xr[d];
    __syncthreads();
    const float* w = gw + (size_t)tid * D_DIM;
    float acc = 0.f;
    #pragma unroll 8
    for (int d = 0; d < D_DIM; ++d) acc = fmaf(xs[d], w[d], acc);
    lgs[tid] = acc;
    __syncthreads();
    if (tid == 0) {
        float mx = -INFINITY;
        for (int e = 0; e < E_NUM; ++e) mx = fmaxf(mx, lgs[e]);
        float se = 0.f;
        for (int e = 0; e < E_NUM; ++e) se += expf(lgs[e] - mx);
        float inv = 1.f / se;
        uint64_t used = 0;
        for (int k = 0; k < K_TOP; ++k) {
            int bi = 0; float bv = -INFINITY;
            for (int e = 0; e < E_NUM; ++e) {
                if (!((used >> e) & 1) && lgs[e] > bv) { bv = lgs[e]; bi = e; }
            }
            used |= 1ull << bi;
            topi[t * K_TOP + k] = bi;
            topw[t * K_TOP + k] = expf(bv - mx) * inv;
        }
    }
}

// ---------------- Slot assignment ----------------
__global__ void assign_k(const int* __restrict__ topi, const float* __restrict__ topw,
        int* __restrict__ cnt, int* __restrict__ rowtok, float* __restrict__ aw, int T) {
    int t = blockIdx.x * blockDim.x + threadIdx.x;
    if (t >= T) return;
    for (int k = 0; k < K_TOP; ++k) {
        int e = topi[t * K_TOP + k];
        int pos = atomicAdd(&cnt[e], 1);
        if (pos < CAP) {
            rowtok[e * CAP + pos] = t;
            aw[e * CAP + pos] = topw[t * K_TOP + k];
        }
    }
}

// ======== Gate+Up: 128m x 128f, BK=32, depth-2 reg pipeline, LDS dbuf ========
#define GU_ISSUE(RA, RG, RU, T) do {                                          \
    RA = *(const uint4*)(ag + (T) * 32);                                      \
    size_t _ko = (size_t)(T) * 32 * F_DIM;                                    \
    RG[0] = *(const float2*)(gp + _ko);                                       \
    RG[1] = *(const float2*)(gp + _ko + F_DIM);                               \
    RG[2] = *(const float2*)(gp + _ko + 2 * F_DIM);                           \
    RG[3] = *(const float2*)(gp + _ko + 3 * F_DIM);                           \
    RU[0] = *(const float2*)(up + _ko);                                       \
    RU[1] = *(const float2*)(up + _ko + F_DIM);                               \
    RU[2] = *(const float2*)(up + _ko + 2 * F_DIM);                           \
    RU[3] = *(const float2*)(up + _ko + 3 * F_DIM);                           \
} while (0)

#define GU_WRITE(RA, RG, RU, B) do {                                          \
    *(uint4*)(&L[B][0][0] + aoff) = RA;                                       \
    uint2 w0, w1;                                                             \
    w0.x = pack2(RG[0].x, RG[1].x); w0.y = pack2(RG[2].x, RG[3].x);           \
    w1.x = pack2(RG[0].y, RG[1].y); w1.y = pack2(RG[2].y, RG[3].y);           \
    *(uint2*)(&L[B][1][0] + boff) = w0;                                       \
    *(uint2*)(&L[B][1][0] + boff + APITCH) = w1;                              \
    w0.x = pack2(RU[0].x, RU[1].x); w0.y = pack2(RU[2].x, RU[3].x);           \
    w1.x = pack2(RU[0].y, RU[1].y); w1.y = pack2(RU[2].y, RU[3].y);           \
    *(uint2*)(&L[B][2][0] + boff) = w0;                                       \
    *(uint2*)(&L[B][2][0] + boff + APITCH) = w1;                              \
} while (0)

#define GU_COMPUTE(B) do {                                                    \
    short8 af[2], bg[4], bu[4];                                               \
    _Pragma("unroll")                                                         \
    for (int mi = 0; mi < 2; ++mi)                                            \
        af[mi] = *(const short8*)(&L[B][0][0] + afr + mi * 16 * APITCH);      \
    _Pragma("unroll")                                                         \
    for (int ni = 0; ni < 4; ++ni) {                                          \
        bg[ni] = *(const short8*)(&L[B][1][0] + bfr + ni * 16 * APITCH);      \
        bu[ni] = *(const short8*)(&L[B][2][0] + bfr + ni * 16 * APITCH);      \
    }                                                                         \
    _Pragma("unroll")                                                         \
    for (int mi = 0; mi < 2; ++mi)                                            \
        _Pragma("unroll")                                                     \
        for (int ni = 0; ni < 4; ++ni) {                                      \
            accg[mi][ni] = __builtin_amdgcn_mfma_f32_16x16x32_bf16(af[mi], bg[ni], accg[mi][ni], 0, 0, 0); \
            accu[mi][ni] = __builtin_amdgcn_mfma_f32_16x16x32_bf16(af[mi], bu[ni], accu[mi][ni], 0, 0, 0); \
        }                                                                     \
} while (0)

__global__ __launch_bounds__(512, 2) void gateup_k(const uint16_t* __restrict__ xb,
        const float* __restrict__ wg, const float* __restrict__ wu,
        const int* __restrict__ cnt, const int* __restrict__ rowtok,
        uint16_t* __restrict__ h) {
    int flat = blockIdx.x;
    int xcd = flat & 7;
    int idx = flat >> 3;
    int m = idx & 7;
    int sloc = idx >> 3;              // 0..63
    int strip = sloc * 8 + xcd;       // e*8 + f
    int e = strip >> 3;
    int f = strip & 7;
    int m0 = m * 128;
    int ne = min(cnt[e], CAP);
    int nr = ne - m0;
    if (nr <= 0) return;
    if (nr > 128) nr = 128;
    int slot0 = e * CAP + m0;
    int fbase = f * 128;

    __shared__ __align__(16) unsigned char L[2][3][128 * APITCH];

    int tid = threadIdx.x;
    // A gather: row = tid/4, chunk = tid%4 (16B of bf16)
    int arow = tid >> 2, ach = tid & 3;
    int tok = rowtok[slot0 + min(arow, nr - 1)];
    const uint16_t* ag = xb + (size_t)tok * D_DIM + ach * 8;
    uint32_t aoff = (uint32_t)arow * APITCH + ach * 16;
    // B: col pair per lane-group, 4 k-rows per thread
    int c0 = (tid & 63) * 2;
    int kg = tid >> 6;                // 0..7 -> k = kg*4..kg*4+3
    size_t wb = (size_t)e * ((size_t)D_DIM * F_DIM) + (size_t)(kg * 4) * F_DIM
              + (size_t)fbase + c0;
    const float* gp = wg + wb;
    const float* up = wu + wb;
    uint32_t boff = (uint32_t)c0 * APITCH + kg * 8;

    int l = tid & 63, wid = tid >> 6;
    int wr = wid >> 1, wc = wid & 1;  // 4m x 2f waves; wave tile 32 x 64
    int ln = l & 15, lq = l >> 4;
    uint32_t afr = (uint32_t)(wr * 32 + ln) * APITCH + lq * 16;
    uint32_t bfr = (uint32_t)(wc * 64 + ln) * APITCH + lq * 16;

    f32x4 accg[2][4], accu[2][4];
    #pragma unroll
    for (int mi = 0; mi < 2; ++mi)
        #pragma unroll
        for (int ni = 0; ni < 4; ++ni) {
            accg[mi][ni] = (f32x4){0.f, 0.f, 0.f, 0.f};
            accu[mi][ni] = (f32x4){0.f, 0.f, 0.f, 0.f};
        }

    uint4 raP, raQ;
    float2 rgP[4], ruP[4], rgQ[4], ruQ[4];

    const int NT = D_DIM / 32;        // 64
    GU_ISSUE(raP, rgP, ruP, 0);
    GU_ISSUE(raQ, rgQ, ruQ, 1);
    GU_WRITE(raP, rgP, ruP, 0);
    __syncthreads();

    for (int t = 0; t < NT; t += 2) {
        if (t + 2 < NT) GU_ISSUE(raP, rgP, ruP, t + 2);
        GU_COMPUTE(0);
        GU_WRITE(raQ, rgQ, ruQ, 1);
        __syncthreads();
        if (t + 3 < NT) GU_ISSUE(raQ, rgQ, ruQ, t + 3);
        GU_COMPUTE(1);
        if (t + 2 < NT) { GU_WRITE(raP, rgP, ruP, 0); }
        __syncthreads();
    }

    #pragma unroll
    for (int mi = 0; mi < 2; ++mi) {
        int rb = wr * 32 + mi * 16 + lq * 4;
        #pragma unroll
        for (int j = 0; j < 4; ++j) {
            int row = rb + j;
            if (row < nr) {
                size_t hb = (size_t)(slot0 + row) * F_DIM + fbase + wc * 64 + ln;
                #pragma unroll
                for (int ni = 0; ni < 4; ++ni) {
                    float g = accg[mi][ni][j], u = accu[mi][ni][j];
                    h[hb + ni * 16] = f_to_bf16(g / (1.f + __expf(-g)) * u);
                }
            }
        }
    }
}

// ======== Down: 128m x 128d, BK=32, depth-2 reg pipeline, LDS dbuf ========
#define DN_ISSUE(RA, RB, T) do {                                              \
    RA = *(const uint4*)(ag + (T) * 32);                                      \
    size_t _ko = (size_t)(T) * 32 * D_DIM;                                    \
    RB[0] = *(const float2*)(bp + _ko);                                       \
    RB[1] = *(const float2*)(bp + _ko + D_DIM);                               \
    RB[2] = *(const float2*)(bp + _ko + 2 * D_DIM);                           \
    RB[3] = *(const float2*)(bp + _ko + 3 * D_DIM);                           \
} while (0)

#define DN_WRITE(RA, RB, B) do {                                              \
    *(uint4*)(&L[B][0][0] + aoff) = RA;                                       \
    uint2 w0, w1;                                                             \
    w0.x = pack2(RB[0].x, RB[1].x); w0.y = pack2(RB[2].x, RB[3].x);           \
    w1.x = pack2(RB[0].y, RB[1].y); w1.y = pack2(RB[2].y, RB[3].y);           \
    *(uint2*)(&L[B][1][0] + boff) = w0;                                       \
    *(uint2*)(&L[B][1][0] + boff + APITCH) = w1;                              \
} while (0)

#define DN_COMPUTE(B) do {                                                    \
    short8 af[2], bf[4];                                                      \
    _Pragma("unroll")                                                         \
    for (int mi = 0; mi < 2; ++mi)                                            \
        af[mi] = *(const short8*)(&L[B][0][0] + afr + mi * 16 * APITCH);      \
    _Pragma("unroll")                                                         \
    for (int ni = 0; ni < 4; ++ni)                                            \
        bf[ni] = *(const short8*)(&L[B][1][0] + bfr + ni * 16 * APITCH);      \
    _Pragma("unroll")                                                         \
    for (int mi = 0; mi < 2; ++mi)                                            \
        _Pragma("unroll")                                                     \
        for (int ni = 0; ni < 4; ++ni)                                        \
            acc[mi][ni] = __builtin_amdgcn_mfma_f32_16x16x32_bf16(af[mi], bf[ni], acc[mi][ni], 0, 0, 0); \
} while (0)

__global__ __launch_bounds__(512, 2) void down_k(const uint16_t* __restrict__ h,
        const float* __restrict__ wd, const int* __restrict__ cnt,
        const int* __restrict__ rowtok, const float* __restrict__ aw,
        float* __restrict__ out) {
    int flat = blockIdx.x;
    int xcd = flat & 7;
    int idx = flat >> 3;
    int m = idx & 7;
    int sloc = idx >> 3;              // 0..127
    int strip = sloc * 8 + xcd;       // e*16 + dt
    int e = strip >> 4;
    int dt = strip & 15;
    int m0 = m * 128;
    int ne = min(cnt[e], CAP);
    int nr = ne - m0;
    if (nr <= 0) return;
    if (nr > 128) nr = 128;
    int slot0 = e * CAP + m0;
    int dbase = dt * 128;

    __shared__ __align__(16) unsigned char L[2][2][128 * APITCH];

    int tid = threadIdx.x;
    int arow = tid >> 2, ach = tid & 3;
    const uint16_t* ag = h + (size_t)(slot0 + min(arow, nr - 1)) * F_DIM + ach * 8;
    uint32_t aoff = (uint32_t)arow * APITCH + ach * 16;

    int c0 = (tid & 63) * 2;
    int kg = tid >> 6;
    const float* bp = wd + (size_t)e * ((size_t)F_DIM * D_DIM) + (size_t)(kg * 4) * D_DIM
                    + (size_t)dbase + c0;
    uint32_t boff = (uint32_t)c0 * APITCH + kg * 8;

    int l = tid & 63, wid = tid >> 6;
    int wr = wid >> 1, wc = wid & 1;
    int ln = l & 15, lq = l >> 4;
    uint32_t afr = (uint32_t)(wr * 32 + ln) * APITCH + lq * 16;
    uint32_t bfr = (uint32_t)(wc * 64 + ln) * APITCH + lq * 16;

    f32x4 acc[2][4];
    #pragma unroll
    for (int mi = 0; mi < 2; ++mi)
        #pragma unroll
        for (int ni = 0; ni < 4; ++ni)
            acc[mi][ni] = (f32x4){0.f, 0.f, 0.f, 0.f};

    uint4 raP, raQ;
    float2 rbP[4], rbQ[4];

    const int NT = F_DIM / 32;        // 32
    DN_ISSUE(raP, rbP, 0);
    DN_ISSUE(raQ, rbQ, 1);
    DN_WRITE(raP, rbP, 0);
    __syncthreads();

    for (int t = 0; t < NT; t += 2) {
        if (t + 2 < NT) DN_ISSUE(raP, rbP, t + 2);
        DN_COMPUTE(0);
        DN_WRITE(raQ, rbQ, 1);
        __syncthreads();
        if (t + 3 < NT) DN_ISSUE(raQ, rbQ, t + 3);
        DN_COMPUTE(1);
        if (t + 2 < NT) { DN_WRITE(raP, rbP, 0); }
        __syncthreads();
    }

    #pragma unroll
    for (int mi = 0; mi < 2; ++mi) {
        int rb2 = wr * 32 + mi * 16 + lq * 4;
        #pragma unroll
        for (int j = 0; j < 4; ++j) {
            int row = rb2 + j;
            if (row < nr) {
                int slot = slot0 + row;
                int tok = rowtok[slot];
                float wgt = aw[slot];
                float* orow = out + (size_t)tok * D_DIM + dbase + wc * 64 + ln;
                #pragma unroll
                for (int ni = 0; ni < 4; ++ni)
                    atomicAdd(&orow[ni * 16], acc[mi][ni][j] * wgt);
            }
        }
    }
}

extern "C" void kernel_launch(void* const* d_in, const int* in_sizes, int n_in,
                              void* d_out, int out_size, void* d_ws, size_t ws_size,
                              hipStream_t stream) {
    const float* x  = (const float*)d_in[0];
    const float* gw = (const float*)d_in[1];
    const float* wg = (const float*)d_in[2];
    const float* wu = (const float*)d_in[3];
    const float* wd = (const float*)d_in[4];
    float* out = (float*)d_out;
    int T = in_sizes[0] / D_DIM;

    char* ws = (char*)d_ws;
    size_t off = 0;
    auto alloc = [&](size_t bytes) -> void* {
        void* p = ws + off;
        off = (off + bytes + 255) & ~(size_t)255;
        return p;
    };
    int*      cnt    = (int*)     alloc(E_NUM * sizeof(int));
    int*      topi   = (int*)     alloc((size_t)T * K_TOP * sizeof(int));
    float*    topw   = (float*)   alloc((size_t)T * K_TOP * sizeof(float));
    int*      rowtok = (int*)     alloc((size_t)E_NUM * CAP * sizeof(int));
    float*    aw     = (float*)   alloc((size_t)E_NUM * CAP * sizeof(float));
    uint16_t* xb     = (uint16_t*)alloc((size_t)T * D_DIM * sizeof(uint16_t));
    uint16_t* h      = (uint16_t*)alloc((size_t)E_NUM * CAP * F_DIM * sizeof(uint16_t));

    hipMemsetAsync(cnt, 0, E_NUM * sizeof(int), stream);
    hipMemsetAsync(out, 0, (size_t)out_size * sizeof(float), stream);

    int n8 = T * D_DIM / 8;
    cvtx_k<<<(n8 + 255) / 256, 256, 0, stream>>>(x, xb, n8);
    router_k<<<T, 64, 0, stream>>>(x, gw, topi, topw);
    assign_k<<<(T + 255) / 256, 256, 0, stream>>>(topi, topw, cnt, rowtok, aw, T);
    gateup_k<<<E_NUM * 8 * 8, 512, 0, stream>>>(xb, wg, wu, cnt, rowtok, h);
    down_k<<<E_NUM * 16 * 8, 512, 0, stream>>>(h, wd, cnt, rowtok, aw, out);
}